// Round 11
// baseline (83.776 us; speedup 1.0000x reference)
//
#include <hip/hip_runtime.h>
#include <hip/hip_bf16.h>
#include <stdint.h>

// Problem constants: N=8192 tokens, D=1024, U=512, E=8, B=8 bases.
#define NTOK 8192
#define DDIM 1024
#define UDIM 512
#define NEXP 8
#define MT_MAX 136   // max padded 64-row M-tiles: 8192/64 + 7 partials + slack

typedef __attribute__((ext_vector_type(8))) short bf16x8;
typedef __attribute__((ext_vector_type(4))) float f32x4;

// ---- helpers ---------------------------------------------------------------

__device__ __forceinline__ unsigned short f2bf(float f) {
  unsigned int u = __float_as_uint(f);
  u += 0x7FFFu + ((u >> 16) & 1u);
  return (unsigned short)(u >> 16);
}

__device__ __forceinline__ void gload16(const void* g, void* lds) {
  // async global->LDS, 16B/lane; LDS dest = wave-uniform base + lane*16 (HW rule);
  // global source address is per-lane (gather allowed).
  __builtin_amdgcn_global_load_lds(
      (__attribute__((address_space(1))) void*)(uintptr_t)g,
      (__attribute__((address_space(3))) void*)(uint32_t)(uintptr_t)lds,
      16, 0, 0);
}

// ---- fused prep+pack: block-range split ------------------------------------
// blocks [0,512): gating, 16 tokens/block (4/wave) + x -> bf16
// blocks [512,2560): weight packing [E][R][C] f32 -> [kt][C][32] bf16 panels

__global__ __launch_bounds__(256) void k_prep_pack(
    const float* __restrict__ x, const float* __restrict__ Wg,
    const float* __restrict__ bg, const float* __restrict__ W1,
    const float* __restrict__ proj, unsigned short* __restrict__ xbf,
    int* __restrict__ eidx, unsigned short* __restrict__ W1p,
    unsigned short* __restrict__ projp) {
  __shared__ __align__(16) char smem[8 * 1040 * 4];  // union: WgT | pack tile
  const int t = threadIdx.x;

  if (blockIdx.x < 512) {
    // ---- gating + bf16 conversion: 4 waves x 4 tokens ----
    float (*WgT)[1040] = (float(*)[1040])smem;
#pragma unroll
    for (int r = 0; r < 32; ++r)
      WgT[t & 7][r * 32 + (t >> 3)] = Wg[r * 256 + t];
    __syncthreads();

    const int lane = t & 63;
    const int wid = t >> 6;
    const int n0 = (blockIdx.x << 4) + (wid << 2);
    float acc[4][8];
#pragma unroll
    for (int i = 0; i < 4; ++i)
#pragma unroll
      for (int e = 0; e < 8; ++e) acc[i][e] = 0.f;

#pragma unroll
    for (int c = 0; c < 4; ++c) {
      const int d = c * 256 + lane * 4;
      float4 xv[4];
#pragma unroll
      for (int i = 0; i < 4; ++i)
        xv[i] = *(const float4*)(x + (size_t)(n0 + i) * DDIM + d);
      // write bf16 copies
#pragma unroll
      for (int i = 0; i < 4; ++i) {
        ushort4 o;
        o.x = f2bf(xv[i].x); o.y = f2bf(xv[i].y); o.z = f2bf(xv[i].z); o.w = f2bf(xv[i].w);
        *(ushort4*)(xbf + (size_t)(n0 + i) * DDIM + d) = o;
      }
#pragma unroll
      for (int e = 0; e < 8; ++e) {
        const float4 wv = *(const float4*)(&WgT[e][d]);
#pragma unroll
        for (int i = 0; i < 4; ++i) {
          acc[i][e] = fmaf(xv[i].x, wv.x, acc[i][e]);
          acc[i][e] = fmaf(xv[i].y, wv.y, acc[i][e]);
          acc[i][e] = fmaf(xv[i].z, wv.z, acc[i][e]);
          acc[i][e] = fmaf(xv[i].w, wv.w, acc[i][e]);
        }
      }
    }
#pragma unroll
    for (int i = 0; i < 4; ++i)
#pragma unroll
      for (int e = 0; e < 8; ++e) {
#pragma unroll
        for (int o = 32; o > 0; o >>= 1) acc[i][e] += __shfl_xor(acc[i][e], o, 64);
      }
    if (lane == 0) {
#pragma unroll
      for (int i = 0; i < 4; ++i) {
        int best = 0;
        float bv = acc[i][0] + bg[0];
#pragma unroll
        for (int e2 = 1; e2 < 8; ++e2) {
          const float v = acc[i][e2] + bg[e2];
          if (v > bv) { bv = v; best = e2; }  // strict > = np.argmax first-index ties
        }
        eidx[n0 + i] = best;
      }
    }
  } else {
    // ---- weight packing ----
    float (*tile)[65] = (float(*)[65])smem;
    const int id = blockIdx.x - 512;
    const int c0 = (id & 7) << 6;
    const int r0 = ((id >> 3) & 15) << 6;
    const int z = id >> 7;  // 0..15
    const int R = (z < 8) ? DDIM : UDIM;
    if (r0 >= R) return;
    const float* src = (z < 8) ? (W1 + (size_t)z * DDIM * UDIM)
                               : (proj + (size_t)(z - 8) * UDIM * UDIM);
    unsigned short* dst = (z < 8) ? (W1p + (size_t)z * DDIM * UDIM)
                                  : (projp + (size_t)(z - 8) * UDIM * UDIM);
#pragma unroll
    for (int i = 0; i < 4; ++i) {
      const int ri = (t >> 4) + i * 16;
      const int ci = (t & 15) * 4;
      const float4 v = *(const float4*)(src + (size_t)(r0 + ri) * UDIM + c0 + ci);
      tile[ri][ci] = v.x; tile[ri][ci + 1] = v.y; tile[ri][ci + 2] = v.z; tile[ri][ci + 3] = v.w;
    }
    __syncthreads();
    const int cc = t >> 2, ch = t & 3;
#pragma unroll
    for (int j = 0; j < 2; ++j) {
      const int kt = (r0 >> 5) + j;
      union { bf16x8 v; unsigned short u[8]; } pk;
#pragma unroll
      for (int q = 0; q < 8; ++q) pk.u[q] = f2bf(tile[j * 32 + ch * 8 + q][cc]);
      *(bf16x8*)(dst + ((size_t)kt * UDIM + c0 + cc) * 32 + ch * 8) = pk.v;
    }
  }
}

// ---- sort: wave-shuffle scans, 3 barriers, ZERO atomics --------------------

__global__ __launch_bounds__(1024) void k_sort(const int* __restrict__ eidx,
                                               int* __restrict__ perm_p,
                                               int* __restrict__ tile_expert,
                                               int* __restrict__ tile_rowlim) {
  __shared__ int wavetot[8][16];
  __shared__ int tot[8];
  __shared__ int tbase[9];
  const int t = threadIdx.x;
  const int lane = t & 63, wid = t >> 6;

  int my[8], c[8] = {0, 0, 0, 0, 0, 0, 0, 0};
#pragma unroll
  for (int i = 0; i < 8; ++i) {
    my[i] = eidx[t * 8 + i];
#pragma unroll
    for (int b = 0; b < 8; ++b) c[b] += (my[i] == b);
  }

  int inc[8];
#pragma unroll
  for (int b = 0; b < 8; ++b) {
    int v = c[b];
#pragma unroll
    for (int o = 1; o < 64; o <<= 1) {
      const int u = __shfl_up(v, o, 64);
      if (lane >= o) v += u;
    }
    inc[b] = v;
  }
  if (lane == 63) {
#pragma unroll
    for (int b = 0; b < 8; ++b) wavetot[b][wid] = inc[b];
  }
  __syncthreads();

  if (t < 8) {
    int run = 0;
#pragma unroll
    for (int w2 = 0; w2 < 16; ++w2) {
      const int u = wavetot[t][w2];
      wavetot[t][w2] = run;
      run += u;
    }
    tot[t] = run;
  }
  __syncthreads();
  if (t == 0) {
    int run = 0;
    for (int e = 0; e < 8; ++e) { tbase[e] = run; run += (tot[e] + 63) >> 6; }
    tbase[8] = run;
  }
  __syncthreads();

  int base[8];
#pragma unroll
  for (int b = 0; b < 8; ++b)
    base[b] = (tbase[b] << 6) + wavetot[b][wid] + inc[b] - c[b];
#pragma unroll
  for (int b = 0; b < 8; ++b) {
    int p = base[b];
#pragma unroll
    for (int i = 0; i < 8; ++i)
      if (my[i] == b) perm_p[p++] = t * 8 + i;
  }

  if (t < MT_MAX) {
    int e = -1, rl = 0;
#pragma unroll
    for (int q = 0; q < 8; ++q) {
      if (t >= tbase[q] && t < tbase[q + 1]) {
        e = q;
        const int r = tot[q] - (t - tbase[q]) * 64;
        rl = r < 64 ? r : 64;
      }
    }
    tile_expert[t] = e;
    tile_rowlim[t] = rl;
  }
}

// ---- GEMM1: H = swish(xbf[tok] @ W1[e] + b1[e]) -> Hp panels bf16 ----------
// 64x32 tile, BK=32, 4 waves (each 16x32 out), 12.3KB LDS dbuf ->
// grid 2176 = 8.5 blocks/CU -> ~32 waves/CU (grid was the occupancy limiter).

__global__ __launch_bounds__(256, 8) void k_gemm1(
    const unsigned short* __restrict__ xbf, const unsigned short* __restrict__ W1p,
    const float* __restrict__ b1, const int* __restrict__ perm_p,
    const int* __restrict__ tile_expert, const int* __restrict__ tile_rowlim,
    unsigned short* __restrict__ Hp) {
  __shared__ __align__(16) short Ab[2][64 * 32];
  __shared__ __align__(16) short Bb[2][32 * 32];
  __shared__ int rows_s[64];

  const int orig = blockIdx.x;                       // 0..2175, 8 XCD chunks of 272
  const int wg = (orig & 7) * 272 + (orig >> 3);
  const int Mt = wg >> 4, Nt = wg & 15;              // 17 Mt x 16 Nt per XCD
  const int e = tile_expert[Mt];
  if (e < 0) return;
  const int rowlim = tile_rowlim[Mt];

  const int t = threadIdx.x;
  const int w = t >> 6;                              // wave 0..3 -> rows w*16..w*16+15
  const int lane = t & 63, ln15 = lane & 15, g = lane >> 4;

  if (t < 64) rows_s[t] = perm_p[Mt * 64 + (t < rowlim ? t : 0)];
  __syncthreads();

  const int arow = t >> 2;                       // staged A row 0..63
  const int ah = (t & 3) ^ ((arow >> 1) & 3);    // pre-swizzled source chunk
  const unsigned short* asrc = xbf + (size_t)rows_s[arow] * DDIM + ah * 8;
  const int bcol = t >> 2;                       // staged B col 0..31 (t<128)
  const int bh = (t & 3) ^ ((bcol >> 1) & 3);
  const unsigned short* Bpan = W1p + ((size_t)e * 32 * UDIM + Nt * 32) * 32;

  auto stage = [&](int kt, int buf) {
    gload16(asrc + kt * 32, (char*)Ab[buf] + (t & ~63) * 16);
    if (t < 128)
      gload16(Bpan + (size_t)kt * UDIM * 32 + bcol * 32 + bh * 8,
              (char*)Bb[buf] + (t & ~63) * 16);
  };

  f32x4 acc[2];
  const f32x4 z4 = {0.f, 0.f, 0.f, 0.f};
  acc[0] = z4; acc[1] = z4;

  stage(0, 0);
  __syncthreads();
  int cur = 0;
  const int r = w * 16 + ln15;
  const int aslot = g ^ ((r >> 1) & 3);
  for (int kt = 0; kt < 32; ++kt) {
    const int nb = cur ^ 1;
    if (kt < 31) stage(kt + 1, nb);
    bf16x8 af, bf_[2];
    af = *(const bf16x8*)((const char*)Ab[cur] + r * 64 + aslot * 16);
#pragma unroll
    for (int nt = 0; nt < 2; ++nt) {
      const int c2 = nt * 16 + ln15;
      bf_[nt] = *(const bf16x8*)((const char*)Bb[cur] + c2 * 64 + (g ^ ((c2 >> 1) & 3)) * 16);
    }
#pragma unroll
    for (int nt = 0; nt < 2; ++nt)
      acc[nt] = __builtin_amdgcn_mfma_f32_16x16x32_bf16(af, bf_[nt], acc[nt], 0, 0, 0);
    __syncthreads();
    cur = nb;
  }

  // epilogue: +b1, swish (rcp-based), store bf16 into Hp panel [Mt][16][64][32]
  unsigned short* hp = Hp + ((size_t)(Mt * 16 + Nt) * 64) * 32;
#pragma unroll
  for (int nt = 0; nt < 2; ++nt) {
    const int cin = nt * 16 + ln15;
    const float bv = b1[e * UDIM + Nt * 32 + cin];
#pragma unroll
    for (int rr = 0; rr < 4; ++rr) {
      const int row = w * 16 + g * 4 + rr;     // C layout: row=(lane>>4)*4+reg
      const float a = acc[nt][rr] + bv;
      hp[row * 32 + cin] = f2bf(a * __builtin_amdgcn_rcpf(1.f + __expf(-a)));
    }
  }
}

// ---- GEMM2: Z = H @ proj[e]; fused sigmoid->RBF->ctrl->scale->scatter ------
// Same 64x32 tiling / grid 2176.

__global__ __launch_bounds__(256, 8) void k_gemm2(
    const unsigned short* __restrict__ Hp, const unsigned short* __restrict__ projp,
    const float* __restrict__ ctrl, const float* __restrict__ scaling,
    const int* __restrict__ perm_p, const int* __restrict__ tile_expert,
    const int* __restrict__ tile_rowlim, float* __restrict__ out) {
  __shared__ __align__(16) short Ab[2][64 * 32];
  __shared__ __align__(16) short Bb[2][32 * 32];
  __shared__ int tok_s[64];

  const int orig = blockIdx.x;
  const int wg = (orig & 7) * 272 + (orig >> 3);
  const int Mt = wg >> 4, Nt = wg & 15;
  const int e = tile_expert[Mt];
  if (e < 0) return;
  const int rowlim = tile_rowlim[Mt];

  const int t = threadIdx.x;
  const int w = t >> 6;
  const int lane = t & 63, ln15 = lane & 15, g = lane >> 4;

  if (t < 64) tok_s[t] = perm_p[Mt * 64 + (t < rowlim ? t : 0)];
  __syncthreads();

  const int arow = t >> 2;
  const int ah = (t & 3) ^ ((arow >> 1) & 3);
  const int bcol = t >> 2;
  const int bh = (t & 3) ^ ((bcol >> 1) & 3);
  const unsigned short* Apan = Hp + ((size_t)Mt * 16 * 64) * 32;
  const unsigned short* Bpan = projp + ((size_t)e * 16 * UDIM + Nt * 32) * 32;

  auto stage = [&](int kt, int buf) {
    gload16(Apan + (size_t)kt * 64 * 32 + arow * 32 + ah * 8,
            (char*)Ab[buf] + (t & ~63) * 16);
    if (t < 128)
      gload16(Bpan + (size_t)kt * UDIM * 32 + bcol * 32 + bh * 8,
              (char*)Bb[buf] + (t & ~63) * 16);
  };

  f32x4 acc[2];
  const f32x4 z4 = {0.f, 0.f, 0.f, 0.f};
  acc[0] = z4; acc[1] = z4;

  stage(0, 0);
  __syncthreads();
  int cur = 0;
  const int r = w * 16 + ln15;
  const int aslot = g ^ ((r >> 1) & 3);
  for (int kt = 0; kt < 16; ++kt) {
    const int nb = cur ^ 1;
    if (kt < 15) stage(kt + 1, nb);
    bf16x8 af, bf_[2];
    af = *(const bf16x8*)((const char*)Ab[cur] + r * 64 + aslot * 16);
#pragma unroll
    for (int nt = 0; nt < 2; ++nt) {
      const int c2 = nt * 16 + ln15;
      bf_[nt] = *(const bf16x8*)((const char*)Bb[cur] + c2 * 64 + (g ^ ((c2 >> 1) & 3)) * 16);
    }
#pragma unroll
    for (int nt = 0; nt < 2; ++nt)
      acc[nt] = __builtin_amdgcn_mfma_f32_16x16x32_bf16(af, bf_[nt], acc[nt], 0, 0, 0);
    __syncthreads();
    cur = nb;
  }

  // epilogue: sigmoid -> RBF via geometric recurrence -> ctrl dot -> scale.
  const float M = 0.27086949f;  // exp(-64/49)
  float cv[2][8], sc[2];
#pragma unroll
  for (int nt = 0; nt < 2; ++nt) {
    const int colg = Nt * 32 + nt * 16 + ln15;
    sc[nt] = scaling[e * UDIM + colg];
#pragma unroll
    for (int b = 0; b < 8; ++b) cv[nt][b] = ctrl[((size_t)e * 8 + b) * UDIM + colg];
  }
#pragma unroll
  for (int rr = 0; rr < 4; ++rr) {
    const int row = w * 16 + g * 4 + rr;
    if (row < rowlim) {
      const int tok = tok_s[row];
#pragma unroll
      for (int nt = 0; nt < 2; ++nt) {
        const int colg = Nt * 32 + nt * 16 + ln15;
        const float z = acc[nt][rr];
        const float xn = __builtin_amdgcn_rcpf(1.f + __expf(-z));
        float q = __expf(-32.f * xn * xn);                     // basis_0
        float rt = __expf(xn * (64.f / 7.f) - (32.f / 49.f));  // step ratio
        float s = 0.f, dc = 0.f;
#pragma unroll
        for (int b = 0; b < 8; ++b) {
          s += q;
          dc = fmaf(q, cv[nt][b], dc);
          q *= rt;
          rt *= M;
        }
        out[(size_t)tok * UDIM + colg] = dc * __builtin_amdgcn_rcpf(s + 1e-6f) * sc[nt];
      }
    }
  }
}

// ---- host launch -----------------------------------------------------------

extern "C" void kernel_launch(void* const* d_in, const int* in_sizes, int n_in,
                              void* d_out, int out_size, void* d_ws, size_t ws_size,
                              hipStream_t stream) {
  const float* x       = (const float*)d_in[0];
  const float* W1      = (const float*)d_in[1];
  const float* b1      = (const float*)d_in[2];
  const float* proj    = (const float*)d_in[3];
  const float* ctrl    = (const float*)d_in[4];
  const float* scaling = (const float*)d_in[5];
  const float* Wg      = (const float*)d_in[6];
  const float* bg      = (const float*)d_in[7];
  float* out = (float*)d_out;
  char* ws = (char*)d_ws;

  // workspace layout (~37.1 MB)
  int* eidx        = (int*)(ws + 0);                 // 32KB
  int* perm_p      = (int*)(ws + 32768);             // 8704*4
  int* tile_expert = (int*)(ws + 69632 + 64);        // 544B
  int* tile_rowlim = (int*)(ws + 69632 + 640);       // 544B
  unsigned short* W1p   = (unsigned short*)(ws + 131072);                        // 8MB
  unsigned short* projp = (unsigned short*)(ws + 131072 + 8388608);              // 4MB
  unsigned short* Hp    = (unsigned short*)(ws + 131072 + 8388608 + 4194304);    // 8.9MB
  unsigned short* xbf   = (unsigned short*)(ws + 131072 + 8388608 + 4194304 + 9175040);  // 16MB

  k_prep_pack<<<2560, 256, 0, stream>>>(x, Wg, bg, W1, proj, xbf, eidx, W1p, projp);
  k_sort<<<1, 1024, 0, stream>>>(eidx, perm_p, tile_expert, tile_rowlim);
  k_gemm1<<<MT_MAX * 16, 256, 0, stream>>>(xbf, W1p, b1, perm_p,
                                           tile_expert, tile_rowlim, Hp);
  k_gemm2<<<MT_MAX * 16, 256, 0, stream>>>(Hp, projp, ctrl, scaling, perm_p,
                                           tile_expert, tile_rowlim, out);
}

// Round 12
// 65.425 us; speedup vs baseline: 1.2805x; 1.2805x over previous
//
#include <hip/hip_runtime.h>
#include <hip/hip_bf16.h>
#include <stdint.h>

// Problem constants: N=8192 tokens, D=1024, U=512, E=8, B=8 bases.
#define NTOK 8192
#define DDIM 1024
#define UDIM 512
#define NEXP 8
#define MT_MAX 136   // max padded 64-row M-tiles: 8192/64 + 7 partials + slack

typedef __attribute__((ext_vector_type(8))) short bf16x8;
typedef __attribute__((ext_vector_type(4))) float f32x4;

// ---- helpers ---------------------------------------------------------------

__device__ __forceinline__ unsigned short f2bf(float f) {
  unsigned int u = __float_as_uint(f);
  u += 0x7FFFu + ((u >> 16) & 1u);
  return (unsigned short)(u >> 16);
}

__device__ __forceinline__ void gload16(const void* g, void* lds) {
  // async global->LDS, 16B/lane; LDS dest = wave-uniform base + lane*16 (HW rule);
  // global source address is per-lane (gather allowed).
  __builtin_amdgcn_global_load_lds(
      (__attribute__((address_space(1))) void*)(uintptr_t)g,
      (__attribute__((address_space(3))) void*)(uint32_t)(uintptr_t)lds,
      16, 0, 0);
}

// ---- fused prep+pack: block-range split ------------------------------------
// blocks [0,512): gating, 16 tokens/block (4/wave) + x -> bf16
// blocks [512,2560): weight packing [E][R][C] f32 -> [kt][C][32] bf16 panels

__global__ __launch_bounds__(256) void k_prep_pack(
    const float* __restrict__ x, const float* __restrict__ Wg,
    const float* __restrict__ bg, const float* __restrict__ W1,
    const float* __restrict__ proj, unsigned short* __restrict__ xbf,
    int* __restrict__ eidx, unsigned short* __restrict__ W1p,
    unsigned short* __restrict__ projp) {
  __shared__ __align__(16) char smem[8 * 1040 * 4];  // union: WgT | pack tile
  const int t = threadIdx.x;

  if (blockIdx.x < 512) {
    // ---- gating + bf16 conversion: 4 waves x 4 tokens ----
    float (*WgT)[1040] = (float(*)[1040])smem;
#pragma unroll
    for (int r = 0; r < 32; ++r)
      WgT[t & 7][r * 32 + (t >> 3)] = Wg[r * 256 + t];
    __syncthreads();

    const int lane = t & 63;
    const int wid = t >> 6;
    const int n0 = (blockIdx.x << 4) + (wid << 2);
    float acc[4][8];
#pragma unroll
    for (int i = 0; i < 4; ++i)
#pragma unroll
      for (int e = 0; e < 8; ++e) acc[i][e] = 0.f;

#pragma unroll
    for (int c = 0; c < 4; ++c) {
      const int d = c * 256 + lane * 4;
      float4 xv[4];
#pragma unroll
      for (int i = 0; i < 4; ++i)
        xv[i] = *(const float4*)(x + (size_t)(n0 + i) * DDIM + d);
#pragma unroll
      for (int i = 0; i < 4; ++i) {
        ushort4 o;
        o.x = f2bf(xv[i].x); o.y = f2bf(xv[i].y); o.z = f2bf(xv[i].z); o.w = f2bf(xv[i].w);
        *(ushort4*)(xbf + (size_t)(n0 + i) * DDIM + d) = o;
      }
#pragma unroll
      for (int e = 0; e < 8; ++e) {
        const float4 wv = *(const float4*)(&WgT[e][d]);
#pragma unroll
        for (int i = 0; i < 4; ++i) {
          acc[i][e] = fmaf(xv[i].x, wv.x, acc[i][e]);
          acc[i][e] = fmaf(xv[i].y, wv.y, acc[i][e]);
          acc[i][e] = fmaf(xv[i].z, wv.z, acc[i][e]);
          acc[i][e] = fmaf(xv[i].w, wv.w, acc[i][e]);
        }
      }
    }
#pragma unroll
    for (int i = 0; i < 4; ++i)
#pragma unroll
      for (int e = 0; e < 8; ++e) {
#pragma unroll
        for (int o = 32; o > 0; o >>= 1) acc[i][e] += __shfl_xor(acc[i][e], o, 64);
      }
    if (lane == 0) {
#pragma unroll
      for (int i = 0; i < 4; ++i) {
        int best = 0;
        float bv = acc[i][0] + bg[0];
#pragma unroll
        for (int e2 = 1; e2 < 8; ++e2) {
          const float v = acc[i][e2] + bg[e2];
          if (v > bv) { bv = v; best = e2; }  // strict > = np.argmax first-index ties
        }
        eidx[n0 + i] = best;
      }
    }
  } else {
    // ---- weight packing ----
    float (*tile)[65] = (float(*)[65])smem;
    const int id = blockIdx.x - 512;
    const int c0 = (id & 7) << 6;
    const int r0 = ((id >> 3) & 15) << 6;
    const int z = id >> 7;  // 0..15
    const int R = (z < 8) ? DDIM : UDIM;
    if (r0 >= R) return;
    const float* src = (z < 8) ? (W1 + (size_t)z * DDIM * UDIM)
                               : (proj + (size_t)(z - 8) * UDIM * UDIM);
    unsigned short* dst = (z < 8) ? (W1p + (size_t)z * DDIM * UDIM)
                                  : (projp + (size_t)(z - 8) * UDIM * UDIM);
#pragma unroll
    for (int i = 0; i < 4; ++i) {
      const int ri = (t >> 4) + i * 16;
      const int ci = (t & 15) * 4;
      const float4 v = *(const float4*)(src + (size_t)(r0 + ri) * UDIM + c0 + ci);
      tile[ri][ci] = v.x; tile[ri][ci + 1] = v.y; tile[ri][ci + 2] = v.z; tile[ri][ci + 3] = v.w;
    }
    __syncthreads();
    const int cc = t >> 2, ch = t & 3;
#pragma unroll
    for (int j = 0; j < 2; ++j) {
      const int kt = (r0 >> 5) + j;
      union { bf16x8 v; unsigned short u[8]; } pk;
#pragma unroll
      for (int q = 0; q < 8; ++q) pk.u[q] = f2bf(tile[j * 32 + ch * 8 + q][cc]);
      *(bf16x8*)(dst + ((size_t)kt * UDIM + c0 + cc) * 32 + ch * 8) = pk.v;
    }
  }
}

// ---- sort: wave-shuffle scans, 3 barriers, ZERO atomics --------------------

__global__ __launch_bounds__(1024) void k_sort(const int* __restrict__ eidx,
                                               int* __restrict__ perm_p,
                                               int* __restrict__ tile_expert,
                                               int* __restrict__ tile_rowlim) {
  __shared__ int wavetot[8][16];
  __shared__ int tot[8];
  __shared__ int tbase[9];
  const int t = threadIdx.x;
  const int lane = t & 63, wid = t >> 6;

  int my[8], c[8] = {0, 0, 0, 0, 0, 0, 0, 0};
#pragma unroll
  for (int i = 0; i < 8; ++i) {
    my[i] = eidx[t * 8 + i];
#pragma unroll
    for (int b = 0; b < 8; ++b) c[b] += (my[i] == b);
  }

  int inc[8];
#pragma unroll
  for (int b = 0; b < 8; ++b) {
    int v = c[b];
#pragma unroll
    for (int o = 1; o < 64; o <<= 1) {
      const int u = __shfl_up(v, o, 64);
      if (lane >= o) v += u;
    }
    inc[b] = v;
  }
  if (lane == 63) {
#pragma unroll
    for (int b = 0; b < 8; ++b) wavetot[b][wid] = inc[b];
  }
  __syncthreads();

  if (t < 8) {
    int run = 0;
#pragma unroll
    for (int w2 = 0; w2 < 16; ++w2) {
      const int u = wavetot[t][w2];
      wavetot[t][w2] = run;
      run += u;
    }
    tot[t] = run;
  }
  __syncthreads();
  if (t == 0) {
    int run = 0;
    for (int e = 0; e < 8; ++e) { tbase[e] = run; run += (tot[e] + 63) >> 6; }
    tbase[8] = run;
  }
  __syncthreads();

  int base[8];
#pragma unroll
  for (int b = 0; b < 8; ++b)
    base[b] = (tbase[b] << 6) + wavetot[b][wid] + inc[b] - c[b];
#pragma unroll
  for (int b = 0; b < 8; ++b) {
    int p = base[b];
#pragma unroll
    for (int i = 0; i < 8; ++i)
      if (my[i] == b) perm_p[p++] = t * 8 + i;
  }

  if (t < MT_MAX) {
    int e = -1, rl = 0;
#pragma unroll
    for (int q = 0; q < 8; ++q) {
      if (t >= tbase[q] && t < tbase[q + 1]) {
        e = q;
        const int r = tot[q] - (t - tbase[q]) * 64;
        rl = r < 64 ? r : 64;
      }
    }
    tile_expert[t] = e;
    tile_rowlim[t] = rl;
  }
}

// ---- GEMM1: H = swish(xbf[tok] @ W1[e] + b1[e]) -> Hp panels bf16 ----------
// 64x128 tile, BK=32, 4 waves (2x2, each 32x64 out), 24KB LDS dbuf.
// Grid 544 = 8 XCD chunks x 17 Mt x 4 Nt. All staging via global_load_lds.

__global__ __launch_bounds__(256) void k_gemm1(
    const unsigned short* __restrict__ xbf, const unsigned short* __restrict__ W1p,
    const float* __restrict__ b1, const int* __restrict__ perm_p,
    const int* __restrict__ tile_expert, const int* __restrict__ tile_rowlim,
    unsigned short* __restrict__ Hp) {
  __shared__ __align__(16) short Ab[2][64 * 32];
  __shared__ __align__(16) short Bb[2][128 * 32];
  __shared__ int rows_s[64];

  const int orig = blockIdx.x;                 // 0..543, 8 XCD chunks of 68
  const int wg = (orig & 7) * 68 + (orig >> 3);
  const int Mt = wg >> 2, Nt = wg & 3;         // per XCD: 17 Mt x 4 Nt
  const int e = tile_expert[Mt];
  if (e < 0) return;
  const int rowlim = tile_rowlim[Mt];

  const int t = threadIdx.x;
  const int w = t >> 6, wr = w >> 1, wc = w & 1;
  const int lane = t & 63, ln15 = lane & 15, g = lane >> 4;

  if (t < 64) rows_s[t] = perm_p[Mt * 64 + (t < rowlim ? t : 0)];
  __syncthreads();

  const int arow = t >> 2;                     // staged A row 0..63
  const int ah = (t & 3) ^ ((arow >> 1) & 3);  // pre-swizzled source chunk
  const unsigned short* asrc = xbf + (size_t)rows_s[arow] * DDIM + ah * 8;
  const unsigned short* Bpan = W1p + ((size_t)e * 32 * UDIM + Nt * 128) * 32;

  auto stage = [&](int kt, int buf) {
    gload16(asrc + kt * 32, (char*)Ab[buf] + (t & ~63) * 16);
#pragma unroll
    for (int j = 0; j < 2; ++j) {
      const int c = t + j * 256;
      const int u2 = c >> 2, h = (c & 3) ^ ((u2 >> 1) & 3);
      gload16(Bpan + (size_t)kt * UDIM * 32 + u2 * 32 + h * 8,
              (char*)Bb[buf] + (c & ~63) * 16);
    }
  };

  f32x4 acc[2][4];
  const f32x4 z4 = {0.f, 0.f, 0.f, 0.f};
#pragma unroll
  for (int a = 0; a < 2; ++a)
#pragma unroll
    for (int b = 0; b < 4; ++b) acc[a][b] = z4;

  stage(0, 0);
  __syncthreads();
  int cur = 0;
  for (int kt = 0; kt < 32; ++kt) {
    const int nb = cur ^ 1;
    if (kt < 31) stage(kt + 1, nb);
    bf16x8 af[2], bf_[4];
#pragma unroll
    for (int mt = 0; mt < 2; ++mt) {
      const int r = wr * 32 + mt * 16 + ln15;
      af[mt] = *(const bf16x8*)((const char*)Ab[cur] + r * 64 + (g ^ ((r >> 1) & 3)) * 16);
    }
#pragma unroll
    for (int nt = 0; nt < 4; ++nt) {
      const int c2 = wc * 64 + nt * 16 + ln15;
      bf_[nt] = *(const bf16x8*)((const char*)Bb[cur] + c2 * 64 + (g ^ ((c2 >> 1) & 3)) * 16);
    }
#pragma unroll
    for (int mt = 0; mt < 2; ++mt)
#pragma unroll
      for (int nt = 0; nt < 4; ++nt)
        acc[mt][nt] = __builtin_amdgcn_mfma_f32_16x16x32_bf16(af[mt], bf_[nt], acc[mt][nt], 0, 0, 0);
    __syncthreads();
    cur = nb;
  }

  // epilogue: +b1, swish (rcp-based), store bf16 into Hp panel [Mt][16][64][32]
  float bv[4];
#pragma unroll
  for (int nt = 0; nt < 4; ++nt)
    bv[nt] = b1[e * UDIM + Nt * 128 + wc * 64 + nt * 16 + ln15];
#pragma unroll
  for (int mt = 0; mt < 2; ++mt) {
#pragma unroll
    for (int nt = 0; nt < 4; ++nt) {
      const int colg = Nt * 128 + wc * 64 + nt * 16 + ln15;
      unsigned short* hp = Hp + ((size_t)(Mt * 16 + (colg >> 5)) * 64) * 32 + (colg & 31);
#pragma unroll
      for (int r = 0; r < 4; ++r) {
        const int row = wr * 32 + mt * 16 + g * 4 + r;
        const float a = acc[mt][nt][r] + bv[nt];
        hp[(size_t)row * 32] = f2bf(a * __builtin_amdgcn_rcpf(1.f + __expf(-a)));
      }
    }
  }
}

// ---- GEMM2: Z = H @ proj[e]; fused sigmoid->RBF->ctrl->scale->scatter ------
// 64x64 tile, BK=32, 4 waves, 16KB LDS dbuf; XCD-chunked grid 1088 (R8 best).

__global__ __launch_bounds__(256) void k_gemm2(
    const unsigned short* __restrict__ Hp, const unsigned short* __restrict__ projp,
    const float* __restrict__ ctrl, const float* __restrict__ scaling,
    const int* __restrict__ perm_p, const int* __restrict__ tile_expert,
    const int* __restrict__ tile_rowlim, float* __restrict__ out) {
  __shared__ __align__(16) short Ab[2][64 * 32];
  __shared__ __align__(16) short Bb[2][64 * 32];
  __shared__ int tok_s[64];

  const int orig = blockIdx.x;
  const int wg = (orig & 7) * MT_MAX + (orig >> 3);
  const int Mt = wg >> 3, Nt = wg & 7;
  const int e = tile_expert[Mt];
  if (e < 0) return;
  const int rowlim = tile_rowlim[Mt];

  const int t = threadIdx.x;
  const int w = t >> 6, wr = w >> 1, wc = w & 1;
  const int lane = t & 63, ln15 = lane & 15, g = lane >> 4;

  if (t < 64) tok_s[t] = perm_p[Mt * 64 + (t < rowlim ? t : 0)];
  __syncthreads();

  const int srow = t >> 2;
  const int sh = (t & 3) ^ ((srow >> 1) & 3);
  const unsigned short* Apan = Hp + ((size_t)Mt * 16 * 64) * 32;
  const unsigned short* Bpan = projp + ((size_t)e * 16 * UDIM + Nt * 64) * 32;

  auto stage = [&](int kt, int buf) {
    gload16(Apan + (size_t)kt * 64 * 32 + srow * 32 + sh * 8,
            (char*)Ab[buf] + (t & ~63) * 16);
    gload16(Bpan + (size_t)kt * UDIM * 32 + srow * 32 + sh * 8,
            (char*)Bb[buf] + (t & ~63) * 16);
  };

  f32x4 acc[2][2];
  const f32x4 z4 = {0.f, 0.f, 0.f, 0.f};
  acc[0][0] = z4; acc[0][1] = z4; acc[1][0] = z4; acc[1][1] = z4;

  stage(0, 0);
  __syncthreads();
  int cur = 0;
  for (int kt = 0; kt < 16; ++kt) {
    const int nb = cur ^ 1;
    if (kt < 15) stage(kt + 1, nb);
    bf16x8 af[2], bf_[2];
#pragma unroll
    for (int mt = 0; mt < 2; ++mt) {
      const int r = wr * 32 + mt * 16 + ln15;
      af[mt] = *(const bf16x8*)((const char*)Ab[cur] + r * 64 + (g ^ ((r >> 1) & 3)) * 16);
    }
#pragma unroll
    for (int nt = 0; nt < 2; ++nt) {
      const int c2 = wc * 32 + nt * 16 + ln15;
      bf_[nt] = *(const bf16x8*)((const char*)Bb[cur] + c2 * 64 + (g ^ ((c2 >> 1) & 3)) * 16);
    }
#pragma unroll
    for (int mt = 0; mt < 2; ++mt)
#pragma unroll
      for (int nt = 0; nt < 2; ++nt)
        acc[mt][nt] = __builtin_amdgcn_mfma_f32_16x16x32_bf16(af[mt], bf_[nt], acc[mt][nt], 0, 0, 0);
    __syncthreads();
    cur = nb;
  }

  // epilogue: sigmoid -> RBF via geometric recurrence -> ctrl dot -> scale.
  const float M = 0.27086949f;  // exp(-64/49)
  float cv[2][8], sc[2];
#pragma unroll
  for (int nt = 0; nt < 2; ++nt) {
    const int colg = Nt * 64 + wc * 32 + nt * 16 + ln15;
    sc[nt] = scaling[e * UDIM + colg];
#pragma unroll
    for (int b = 0; b < 8; ++b) cv[nt][b] = ctrl[((size_t)e * 8 + b) * UDIM + colg];
  }
#pragma unroll
  for (int mt = 0; mt < 2; ++mt) {
#pragma unroll
    for (int r = 0; r < 4; ++r) {
      const int row = wr * 32 + mt * 16 + g * 4 + r;
      if (row < rowlim) {
        const int tok = tok_s[row];
#pragma unroll
        for (int nt = 0; nt < 2; ++nt) {
          const int colg = Nt * 64 + wc * 32 + nt * 16 + ln15;
          const float z = acc[mt][nt][r];
          const float xn = __builtin_amdgcn_rcpf(1.f + __expf(-z));
          float q = __expf(-32.f * xn * xn);                     // basis_0
          float rr = __expf(xn * (64.f / 7.f) - (32.f / 49.f));  // step ratio
          float s = 0.f, dc = 0.f;
#pragma unroll
          for (int b = 0; b < 8; ++b) {
            s += q;
            dc = fmaf(q, cv[nt][b], dc);
            q *= rr;
            rr *= M;
          }
          out[(size_t)tok * UDIM + colg] = dc * __builtin_amdgcn_rcpf(s + 1e-6f) * sc[nt];
        }
      }
    }
  }
}

// ---- host launch -----------------------------------------------------------

extern "C" void kernel_launch(void* const* d_in, const int* in_sizes, int n_in,
                              void* d_out, int out_size, void* d_ws, size_t ws_size,
                              hipStream_t stream) {
  const float* x       = (const float*)d_in[0];
  const float* W1      = (const float*)d_in[1];
  const float* b1      = (const float*)d_in[2];
  const float* proj    = (const float*)d_in[3];
  const float* ctrl    = (const float*)d_in[4];
  const float* scaling = (const float*)d_in[5];
  const float* Wg      = (const float*)d_in[6];
  const float* bg      = (const float*)d_in[7];
  float* out = (float*)d_out;
  char* ws = (char*)d_ws;

  // workspace layout (~37.1 MB)
  int* eidx        = (int*)(ws + 0);                 // 32KB
  int* perm_p      = (int*)(ws + 32768);             // 8704*4
  int* tile_expert = (int*)(ws + 69632 + 64);        // 544B
  int* tile_rowlim = (int*)(ws + 69632 + 640);       // 544B
  unsigned short* W1p   = (unsigned short*)(ws + 131072);                        // 8MB
  unsigned short* projp = (unsigned short*)(ws + 131072 + 8388608);              // 4MB
  unsigned short* Hp    = (unsigned short*)(ws + 131072 + 8388608 + 4194304);    // 8.9MB
  unsigned short* xbf   = (unsigned short*)(ws + 131072 + 8388608 + 4194304 + 9175040);  // 16MB

  k_prep_pack<<<2560, 256, 0, stream>>>(x, Wg, bg, W1, proj, xbf, eidx, W1p, projp);
  k_sort<<<1, 1024, 0, stream>>>(eidx, perm_p, tile_expert, tile_rowlim);
  k_gemm1<<<544, 256, 0, stream>>>(xbf, W1p, b1, perm_p,
                                   tile_expert, tile_rowlim, Hp);
  k_gemm2<<<MT_MAX * 8, 256, 0, stream>>>(Hp, projp, ctrl, scaling, perm_p,
                                          tile_expert, tile_rowlim, out);
}